// Round 4
// baseline (86.225 us; speedup 1.0000x reference)
//
#include <hip/hip_runtime.h>
#include <hip/hip_bf16.h>
#include <math.h>

#define BATCH 512
#define FEAT  256
#define NCLS  100000
#define SCALE_ 32.0f
#define M0_    0.5f
#define MMIN_  0.25f

#define BN 128                       // classes per tile
#define NT 782                       // ceil(100000/128)
#define NSLOT 128                    // class-tile stride
#define NPART 256                    // partial slots per sample (128 nslot x 2 wcls)
#define K4CHUNK 16
#define NK4 (NPART / K4CHUNK)        // 16

typedef unsigned short u16;
typedef short s16x8 __attribute__((ext_vector_type(8)));
typedef float f32x4 __attribute__((ext_vector_type(4)));

// ---- static device scratch ----
__device__ u16   g_wbf16[NCLS * FEAT];     // normalized W rows, bf16
__device__ u16   g_fbf16[BATCH * FEAT];    // normalized features, bf16
__device__ float g_norms[BATCH];
__device__ float g_dot[BATCH];             // raw f32 feat . W[label]
__device__ float g_wn2[BATCH];             // ||W[label]||^2 (f32)
__device__ float g_pmax[NPART * BATCH];
__device__ float g_psum[NPART * BATCH];
__device__ float g_qm[NK4 * BATCH];
__device__ float g_qs[NK4 * BATCH];
__device__ int   g_lab32;                  // 1 if labels arrived as int32

__device__ __forceinline__ u16 f2b(float x) {
  union { float f; unsigned u; } v; v.f = x;
  unsigned r = v.u + 0x7FFFu + ((v.u >> 16) & 1u);   // RNE
  return (u16)(r >> 16);
}

__device__ __forceinline__ void gld_lds16(const void* g, void* l) {
  __builtin_amdgcn_global_load_lds(
      (const __attribute__((address_space(1))) void*)g,
      (__attribute__((address_space(3))) void*)l, 16, 0, 0);
}

// K1a: per-row feature norm; store NORMALIZED bf16 row. One wave per row.
// Block 0 wave 0 additionally detects label width (int32 vs int64).
__global__ void k1a(const float* __restrict__ feat, const int* __restrict__ labw) {
  int wid = threadIdx.x >> 6, lane = threadIdx.x & 63;
  int row = blockIdx.x * 4 + wid;
  float4 f = ((const float4*)(feat + row * FEAT))[lane];
  float ss = f.x * f.x + f.y * f.y + f.z * f.z + f.w * f.w;
  #pragma unroll
  for (int d = 1; d < 64; d <<= 1) ss += __shfl_xor(ss, d, 64);
  float nrm = sqrtf(ss);
  float inv = 1.0f / fmaxf(nrm, 1e-12f);
  ushort4 h;
  h.x = f2b(f.x * inv); h.y = f2b(f.y * inv);
  h.z = f2b(f.z * inv); h.w = f2b(f.w * inv);
  ((ushort4*)(g_fbf16 + row * FEAT))[lane] = h;
  if (lane == 0) g_norms[row] = nrm;
  // label width detect: if any odd 32-bit word of the first 256 labels-as-int64
  // is nonzero, the buffer is int32. (Odd words of int64 labels are 0.)
  if (blockIdx.x == 0 && wid == 0) {
    int odd = 0;
    #pragma unroll
    for (int k = 0; k < 4; ++k) odd |= labw[2 * (k * 64 + lane) + 1];
    unsigned long long b = __ballot(odd != 0);
    if (lane == 0) g_lab32 = (b != 0ULL) ? 1 : 0;
  }
}

// K2: weight row norm; store NORMALIZED bf16 row. One wave per class.
__global__ void k2(const float* __restrict__ wmat) {
  int wid = threadIdx.x >> 6, lane = threadIdx.x & 63;
  int row = blockIdx.x * 4 + wid;   // 25000*4 = 100000
  float4 f = ((const float4*)(wmat + (size_t)row * FEAT))[lane];
  float ss = f.x * f.x + f.y * f.y + f.z * f.z + f.w * f.w;
  #pragma unroll
  for (int d = 1; d < 64; d <<= 1) ss += __shfl_xor(ss, d, 64);
  float inv = 1.0f / fmaxf(sqrtf(ss), 1e-12f);
  ushort4 h;
  h.x = f2b(f.x * inv); h.y = f2b(f.y * inv);
  h.z = f2b(f.z * inv); h.w = f2b(f.w * inv);
  ((ushort4*)(g_wbf16 + (size_t)row * FEAT))[lane] = h;
}

// K2c: raw f32 dot(feat_i, W[label_i]) and ||W[label_i]||^2. One wave per row.
__global__ void k2c(const float* __restrict__ feat, const float* __restrict__ wmat,
                    const void* __restrict__ labels) {
  int wid = threadIdx.x >> 6, lane = threadIdx.x & 63;
  int i = blockIdx.x * 4 + wid;
  long long lab;
  if (g_lab32) lab = (long long)((const int*)labels)[i];
  else         lab = ((const long long*)labels)[i];
  float4 a = ((const float4*)(feat + i * FEAT))[lane];
  float4 b = ((const float4*)(wmat + (size_t)lab * FEAT))[lane];
  float d  = a.x * b.x + a.y * b.y + a.z * b.z + a.w * b.w;
  float bb = b.x * b.x + b.y * b.y + b.z * b.z + b.w * b.w;
  #pragma unroll
  for (int t = 1; t < 64; t <<= 1) {
    d  += __shfl_xor(d, t, 64);
    bb += __shfl_xor(bb, t, 64);
  }
  if (lane == 0) { g_dot[i] = d; g_wn2[i] = bb; }
}

// K3: persistent blocks (1/CU). bid = mt*128 + nslot: mt selects 256 samples
// (held in registers, fr[4][8] per wave), nslot selects class tiles
// {nslot, nslot+128, ...}. W double-buffered in LDS via global_load_lds with
// XOR-swizzled source; 2-phase pipeline, raw barriers + vmcnt(0) at iter end.
// Swapped MFMA (D row=class, col=sample); cls-64 per wave done in two
// half-passes reusing acc[2][4] to cap VGPR pressure.
#define STAGE(BUF, TILE) do {                                              \
    int cb_ = (TILE) * BN;                                                 \
    _Pragma("unroll")                                                      \
    for (int it_ = 0; it_ < 8; ++it_) {                                    \
      int p_ = it_ * 512 + tid;                                            \
      int row_ = p_ >> 5, cc_ = p_ & 31;                                   \
      int cs_ = cc_ ^ (row_ & 7);                                          \
      int grow_ = cb_ + row_; grow_ = grow_ < NCLS ? grow_ : NCLS - 1;     \
      gld_lds16(g_wbf16 + (size_t)grow_ * FEAT + cs_ * 8,                  \
                &Ws[BUF][0] + p_ * 8);                                     \
    }                                                                      \
  } while (0)

__global__ __launch_bounds__(512) void k3() {
  __shared__ __align__(16) u16 Ws[2][BN * FEAT];   // 2 x 64 KB

  const int tid  = threadIdx.x;
  const int lane = tid & 63, wid = tid >> 6;
  const int wsmp = wid >> 1;          // 0..3 : 64-sample group
  const int wcls = wid & 1;           // 0..1 : 64-class group
  const int bid = blockIdx.x;
  const int nslot = bid & 127;
  const int mt = bid >> 7;            // 0..1 : 256-sample half
  const int niter = (nslot < 14) ? 7 : 6;
  const int s = lane & 15, q = lane >> 4;

  STAGE(0, nslot);

  // feature fragments (B-operand), register-resident for the whole loop.
  s16x8 fr[4][8];
  {
    const int srow = mt * 256 + wsmp * 64;
    #pragma unroll
    for (int m = 0; m < 4; ++m)
      #pragma unroll
      for (int c = 0; c < 8; ++c)
        fr[m][c] = *(const s16x8*)(g_fbf16 + (srow + m * 16 + s) * FEAT + c * 32 + q * 8);
  }

  float M[4], S[4];
  #pragma unroll
  for (int m = 0; m < 4; ++m) { M[m] = -1e30f; S[m] = 0.0f; }

  asm volatile("s_waitcnt vmcnt(0)");
  __builtin_amdgcn_s_barrier();

  int buf = 0;
  for (int t = 0; t < niter; ++t) {
    const int tile = nslot + t * NSLOT;
    if (t + 1 < niter) STAGE(buf ^ 1, nslot + (t + 1) * NSLOT);

    const u16* wb = &Ws[buf][0];
    const bool edge = (tile * BN + BN > NCLS);
    const float CLIP = 1.0f - 1e-7f;

    #pragma unroll
    for (int half = 0; half < 2; ++half) {
      f32x4 acc[2][4];
      #pragma unroll
      for (int cf = 0; cf < 2; ++cf)
        #pragma unroll
        for (int m = 0; m < 4; ++m)
          acc[cf][m] = f32x4{0.0f, 0.0f, 0.0f, 0.0f};

      #pragma unroll
      for (int c = 0; c < 8; ++c) {
        s16x8 wf[2];
        #pragma unroll
        for (int cf = 0; cf < 2; ++cf) {
          int row = wcls * 64 + (half * 2 + cf) * 16 + s;
          int cc = c * 4 + q;
          wf[cf] = *(const s16x8*)(wb + row * FEAT + (cc ^ (row & 7)) * 8);
        }
        #pragma unroll
        for (int cf = 0; cf < 2; ++cf)
          #pragma unroll
          for (int m = 0; m < 4; ++m)
            acc[cf][m] = __builtin_amdgcn_mfma_f32_16x16x32_bf16(wf[cf], fr[m][c], acc[cf][m], 0, 0, 0);
      }

      // online (max, sumexp) over this half's 32 classes, per smp-frag
      const int cbase = tile * BN + wcls * 64 + half * 32;
      #pragma unroll
      for (int m = 0; m < 4; ++m) {
        float v[8];
        #pragma unroll
        for (int cf = 0; cf < 2; ++cf)
          #pragma unroll
          for (int r = 0; r < 4; ++r) {
            float cs_ = fminf(fmaxf(acc[cf][m][r], -CLIP), CLIP);
            float lv = SCALE_ * cs_;
            if (edge) {
              int cls = cbase + cf * 16 + q * 4 + r;
              if (cls >= NCLS) lv = -1e30f;
            }
            v[cf * 4 + r] = lv;
          }
        float mx = fmaxf(fmaxf(fmaxf(v[0], v[1]), fmaxf(v[2], v[3])),
                         fmaxf(fmaxf(v[4], v[5]), fmaxf(v[6], v[7])));
        mx = fmaxf(mx, __shfl_xor(mx, 16, 64));
        mx = fmaxf(mx, __shfl_xor(mx, 32, 64));
        float nM = fmaxf(M[m], mx);
        float sl = 0.0f;
        #pragma unroll
        for (int j = 0; j < 8; ++j) sl += __expf(v[j] - nM);
        sl += __shfl_xor(sl, 16, 64);
        sl += __shfl_xor(sl, 32, 64);
        S[m] = S[m] * __expf(M[m] - nM) + sl;
        M[m] = nM;
      }
    }

    asm volatile("s_waitcnt vmcnt(0)");
    __builtin_amdgcn_s_barrier();
    buf ^= 1;
  }

  // partial write: slot = nslot*2 + wcls; lanes 0..15 carry distinct samples.
  if (lane < 16) {
    int pslot = nslot * 2 + wcls;
    #pragma unroll
    for (int m = 0; m < 4; ++m) {
      int smp = mt * 256 + wsmp * 64 + m * 16 + lane;
      g_pmax[pslot * BATCH + smp] = M[m];
      g_psum[pslot * BATCH + smp] = S[m];
    }
  }
}

// K4a: combine 16 of the 256 partial slots per sample per block (coalesced).
__global__ __launch_bounds__(512) void k4a() {
  int i = threadIdx.x;   // sample
  int b = blockIdx.x;    // chunk of partial slots
  float M = -1e30f, S = 0.0f;
  #pragma unroll 4
  for (int p = b * K4CHUNK; p < b * K4CHUNK + K4CHUNK; ++p) {
    float m2 = g_pmax[p * BATCH + i];
    float s2 = g_psum[p * BATCH + i];
    float nM = fmaxf(M, m2);
    S = S * __expf(M - nM) + s2 * __expf(m2 - nM);
    M = nM;
  }
  g_qm[b * BATCH + i] = M;
  g_qs[b * BATCH + i] = S;
}

// K4b: chunk combine + margins (min/max of norms) + target-logit fixup +
// weighted mean.
__global__ void k4b(const float* __restrict__ wts, float* __restrict__ out) {
  int i = threadIdx.x;  // 512
  float M = -1e30f, S = 0.0f;
  #pragma unroll
  for (int t = 0; t < NK4; ++t) {
    float m2 = g_qm[t * BATCH + i];
    float s2 = g_qs[t * BATCH + i];
    float nM = fmaxf(M, m2);
    S = S * __expf(M - nM) + s2 * __expf(m2 - nM);
    M = nM;
  }
  float n = g_norms[i];
  __shared__ float smin[512], smax[512];
  smin[i] = n; smax[i] = n;
  __syncthreads();
  for (int st = 256; st > 0; st >>= 1) {
    if (i < st) {
      smin[i] = fminf(smin[i], smin[i + st]);
      smax[i] = fmaxf(smax[i], smax[i + st]);
    }
    __syncthreads();
  }
  float lo = smin[0], hi = smax[0];
  float denom = fmaxf(hi - lo, 1e-8f);
  float mg = MMIN_ + (M0_ - MMIN_) * (n - lo) / denom;
  mg = fminf(fmaxf(mg, MMIN_), M0_);

  const float CLIP = 1.0f - 1e-7f;
  float wn = fmaxf(sqrtf(g_wn2[i]), 1e-12f);
  float ct = g_dot[i] / (fmaxf(n, 1e-12f) * wn);
  ct = fminf(fmaxf(ct, -CLIP), CLIP);

  float sint = sqrtf(fmaxf(0.0f, 1.0f - ct * ct));
  float cosm = ct * cosf(mg) - sint * sinf(mg);
  float lt_old = SCALE_ * ct, lt_new = SCALE_ * cosm;
  float S2 = S - __expf(lt_old - M) + __expf(lt_new - M);
  float lse = M + logf(S2);
  float contrib = (lse - lt_new) * wts[i];
  __shared__ float sred[512];
  sred[i] = contrib;
  __syncthreads();
  for (int st = 256; st > 0; st >>= 1) {
    if (i < st) sred[i] += sred[i + st];
    __syncthreads();
  }
  if (i == 0) out[0] = sred[0] * (1.0f / (float)BATCH);
}

extern "C" void kernel_launch(void* const* d_in, const int* in_sizes, int n_in,
                              void* d_out, int out_size, void* d_ws, size_t ws_size,
                              hipStream_t stream) {
  const float* feat = (const float*)d_in[0];
  const float* wmat = (const float*)d_in[1];
  const float* wts  = (const float*)d_in[2];
  const void*  labs = d_in[3];
  float* out = (float*)d_out;

  hipLaunchKernelGGL(k1a, dim3(BATCH / 4), dim3(256), 0, stream, feat, (const int*)labs);
  hipLaunchKernelGGL(k2,  dim3(NCLS / 4), dim3(256), 0, stream, wmat);
  hipLaunchKernelGGL(k2c, dim3(BATCH / 4), dim3(256), 0, stream, feat, wmat, labs);
  hipLaunchKernelGGL(k3,  dim3(256), dim3(512), 0, stream);
  hipLaunchKernelGGL(k4a, dim3(NK4), dim3(512), 0, stream);
  hipLaunchKernelGGL(k4b, dim3(1), dim3(512), 0, stream, wts, out);
}